// Round 4
// baseline (73.737 us; speedup 1.0000x reference)
//
#include <hip/hip_runtime.h>
#include <math.h>

// Problem constants (from reference)
#define B_N    32768
#define P_N    128
#define X_N    30
#define Y_N    30
#define F_N    6
#define CELLS  (X_N * Y_N)      // 900
#define ROW_F  (CELLS * F_N)    // 5400 floats per p
#define INV_T  1000.0f          // 1 / 0.001
#define POISON 0xAAAAAAAAu      // harness re-poisons d_ws to 0xAA bytes

// Single dispatch, 256 blocks x 256 threads, ALL-RELAXED sync protocol.
//
// Evidence trail:
//  - r0 baseline (65.2us): per-element poison spin. Proves relaxed agent
//    atomics are cross-XCD visible with NO fences. Cost: ~25us kernel from
//    65536 threads spinning over 57 MALL lines against producer stores.
//  - r2 (89.6us): counter gate with RELEASE add + ACQUIRE fence. Proves the
//    fences are the killer: agent release RMW -> buffer_wbl2, acquire ->
//    buffer_inv, each a 4MiB L2 tag walk on an L2 dirtied by the 256MiB
//    poison fill, x481 instances ~= +22us.
//  - r3 (62.2us): two stream-ordered dispatches. No fences, but pays 2
//    dispatch latencies + full-retirement serialization ~= 21.7us overhead.
//
// This version: single dispatch, single-line counter gate, relaxed-only.
//  - Producer ordering: __syncthreads() emits s_waitcnt vmcnt(0) before
//    s_barrier -> every wave's V store has COMPLETED (reached the coherence
//    point; sc1 atomics ack from MALL) before tid 0 issues the relaxed
//    fetch_add. Ordering by completion — below the C++ model, sound at HW.
//  - Consumer: bounded spin on ONE line (same-address wave loads coalesce),
//    then a compiler-only barrier (zero instructions) stops load hoisting;
//    HW can't hoist: the post-loop loads issue only after the branch
//    resolves on the observed counter value (in-order issue).
//  - Backstop: the r0-proven per-element poison re-check. Transient
//    staleness reads poison -> retries. Stale NON-poison is impossible
//    (d_ws re-poisoned before every launch), so correctness never depends
//    on the counter at all — the gate is purely a traffic optimization.
__global__ __launch_bounds__(256) void fused_kernel(
    const float* __restrict__ phi, const float* __restrict__ sf,
    const float* __restrict__ w, float* __restrict__ V,
    float* __restrict__ out)
{
    const int tid  = threadIdx.x;
    const int lane = tid & 63;
    const int wave = tid >> 6;

    const float w0 = w[0], w1 = w[1], w2 = w[2],
                w3 = w[3], w4 = w[4], w5 = w[5];

    unsigned int* Vu  = (unsigned int*)V;
    unsigned int* cnt = Vu + CELLS;   // d_ws word 900, also poison-initialized

    // ---------------- Phase 1: build V table (blocks 0..224) ----------------
    if (blockIdx.x < 225) {
        const int cell = blockIdx.x * 4 + wave;   // 0..899

        const float* r0 = sf + (size_t)lane * ROW_F + cell * F_N;
        const float* r1 = r0 + (size_t)64 * ROW_F;

        float2 a0 = *(const float2*)(r0);
        float2 a1 = *(const float2*)(r0 + 2);
        float2 a2 = *(const float2*)(r0 + 4);
        float2 b0 = *(const float2*)(r1);
        float2 b1 = *(const float2*)(r1 + 2);
        float2 b2 = *(const float2*)(r1 + 4);

        float d0 = a0.x*w0 + a0.y*w1 + a1.x*w2 + a1.y*w3 + a2.x*w4 + a2.y*w5;
        float d1 = b0.x*w0 + b0.y*w1 + b1.x*w2 + b1.y*w3 + b2.x*w4 + b2.y*w5;

        float m = fmaxf(d0, d1);
#pragma unroll
        for (int off = 32; off >= 1; off >>= 1)
            m = fmaxf(m, __shfl_xor(m, off, 64));

        float e0 = __expf((d0 - m) * INV_T);
        float e1 = __expf((d1 - m) * INV_T);
        float num = e0 * d0 + e1 * d1;
        float den = e0 + e1;
#pragma unroll
        for (int off = 32; off >= 1; off >>= 1) {
            num += __shfl_xor(num, off, 64);
            den += __shfl_xor(den, off, 64);
        }

        if (lane == 0) {
            float val = num / den;
            __hip_atomic_store(&Vu[cell], __float_as_uint(val),
                               __ATOMIC_RELAXED, __HIP_MEMORY_SCOPE_AGENT);
        }

        // Drain V stores (vmcnt(0) at barrier), then ONE relaxed add.
        // NO release: relaxed RMW emits no buffer_wbl2 (the r2 killer).
        __syncthreads();
        if (tid == 0)
            __hip_atomic_fetch_add(cnt, 4u, __ATOMIC_RELAXED,
                                   __HIP_MEMORY_SCOPE_AGENT);
    }

    // ---------------- Phase 2: per-output epilogue (all blocks) -------------
    const int o = blockIdx.x * 256 + tid;   // 0..65535 == B_N*2 outputs
    const int b = o >> 1;
    const int side = o & 1;

    // Prefetch phi BEFORE the gate so HBM latency overlaps the wait.
    // phi layout: [B, 2, 10] -> 20 floats per b, 16B-aligned (80B stride).
    const float4* p4 = (const float4*)(phi + (size_t)b * 20);
    float4 c0 = p4[0];  // t0: f0 f1 f2 f3
    float4 c1 = p4[1];  // t0: f4 f5 x_ss y_ss
    float4 c2 = p4[2];  // t0: x_es y_es | t1: f0 f1
    float4 c3 = p4[3];  // t1: f2 f3 f4 f5
    float4 c4 = p4[4];  // t1: x_ss y_ss x_es y_es

    // Gate: bounded relaxed spin on ONE counter line. No acquire fence
    // (the other r2 killer) — a compiler-only barrier prevents hoisting;
    // the poison backstop below carries correctness regardless.
    {
        unsigned int c = __hip_atomic_load(cnt, __ATOMIC_RELAXED,
                                           __HIP_MEMORY_SCOPE_AGENT);
        int guard = 1 << 22;
        while ((unsigned int)(c - POISON) < (unsigned int)CELLS && --guard) {
            __builtin_amdgcn_s_sleep(1);
            c = __hip_atomic_load(cnt, __ATOMIC_RELAXED,
                                  __HIP_MEMORY_SCOPE_AGENT);
        }
        asm volatile("" ::: "memory");   // compiler reorder fence, 0 instrs
    }

    // Stage V into LDS: 4 independent one-shot loads per thread (single
    // round trip on the fast path). Poison re-check is the proven backstop.
    __shared__ float Vs[CELLS];
    for (int i = tid; i < CELLS; i += 256) {
        unsigned int u = __hip_atomic_load(&Vu[i], __ATOMIC_RELAXED,
                                           __HIP_MEMORY_SCOPE_AGENT);
        while (u == POISON) {
            __builtin_amdgcn_s_sleep(1);
            u = __hip_atomic_load(&Vu[i], __ATOMIC_RELAXED,
                                  __HIP_MEMORY_SCOPE_AGENT);
        }
        Vs[i] = __uint_as_float(u);
    }
    __syncthreads();

    float pr0 = c0.x*w0 + c0.y*w1 + c0.z*w2 + c0.w*w3 + c1.x*w4 + c1.y*w5;
    float pr1 = c2.z*w0 + c2.w*w1 + c3.x*w2 + c3.y*w3 + c3.z*w4 + c3.w*w5;

    int iss0 = (int)c1.z * Y_N + (int)c1.w;
    int ies0 = (int)c2.x * Y_N + (int)c2.y;
    int iss1 = (int)c4.x * Y_N + (int)c4.y;
    int ies1 = (int)c4.z * Y_N + (int)c4.w;

    float d0 = pr0 + Vs[ies0] - Vs[iss0];
    float d1 = pr1 + Vs[ies1] - Vs[iss1];

    float x = side ? (d1 - d0) : (d0 - d1);
    out[o] = 1.0f / (1.0f + expf(-x));
}

// ---------------------------------------------------------------------------
extern "C" void kernel_launch(void* const* d_in, const int* in_sizes, int n_in,
                              void* d_out, int out_size, void* d_ws, size_t ws_size,
                              hipStream_t stream) {
    const float* phi = (const float*)d_in[0];   // (B, 2, 10)
    const float* sf  = (const float*)d_in[1];   // (P, X, Y, F)
    const float* w   = (const float*)d_in[2];   // (F,)
    float* out = (float*)d_out;                 // (B, 2, 1)
    float* V   = (float*)d_ws;                  // 901 floats scratch (poisoned 0xAA)

    fused_kernel<<<256, 256, 0, stream>>>(phi, sf, w, V, out);
}

// Round 5
// 62.409 us; speedup vs baseline: 1.1815x; 1.1815x over previous
//
#include <hip/hip_runtime.h>
#include <math.h>

// Problem constants (from reference)
#define B_N    32768
#define P_N    128
#define X_N    30
#define Y_N    30
#define F_N    6
#define CELLS  (X_N * Y_N)      // 900
#define ROW_F  (CELLS * F_N)    // 5400 floats per p
#define INV_T  1000.0f          // 1 / 0.001

// Two stream-ordered dispatches (r3 structure — best measured: 62.2us).
//
// Sync design history (why stream ordering, not in-kernel sync):
//  - r0 fused + per-element poison spin: kernel ~25us
//  - r2 fused + release/acquire gate:    kernel ~47us (buffer_wbl2/buffer_inv
//    4MiB L2 tag-walks x481 on an L2 dirtied by the 256MiB poison fill)
//  - r4 fused + all-relaxed gate:        kernel ~28us
//  - r3 two dispatches:                  ~21us total incl. both kernels
//  Every intra-kernel sync >= 20us after the fill; dispatch boundary wins.
//
// This round: micro-opt of r3's kernels (the only controllable ~6us slice):
//  k2 one-thread-per-b (halves phi fetch: both sides shared 80B), 256 blocks
//  across 256 CUs, float4 V staging. Per-side arithmetic unchanged ->
//  bitwise-identical outputs to the verified r3 kernel.

// ---------------- Kernel 1: build V table ----------------
// 225 blocks x 256 threads; wave w handles cell = blockIdx*4 + w (225*4=900).
// V[cell] = sum_p softmax_p(s/T)*s,  s = dot(sf[p,cell,:], w).
__global__ __launch_bounds__(256) void v_kernel(
    const float* __restrict__ sf, const float* __restrict__ w,
    float* __restrict__ V)
{
    const int tid  = threadIdx.x;
    const int lane = tid & 63;
    const int wave = tid >> 6;
    const int cell = blockIdx.x * 4 + wave;   // 0..899

    const float w0 = w[0], w1 = w[1], w2 = w[2],
                w3 = w[3], w4 = w[4], w5 = w[5];

    // lane p and p+64; rows are 24B, 8B-aligned -> float2 loads.
    // Waves 0..3 of a block read adjacent 24B rows (cells c..c+3) -> L1 reuse.
    const float* r0 = sf + (size_t)lane * ROW_F + cell * F_N;
    const float* r1 = r0 + (size_t)64 * ROW_F;

    float2 a0 = *(const float2*)(r0);
    float2 a1 = *(const float2*)(r0 + 2);
    float2 a2 = *(const float2*)(r0 + 4);
    float2 b0 = *(const float2*)(r1);
    float2 b1 = *(const float2*)(r1 + 2);
    float2 b2 = *(const float2*)(r1 + 4);

    float d0 = a0.x*w0 + a0.y*w1 + a1.x*w2 + a1.y*w3 + a2.x*w4 + a2.y*w5;
    float d1 = b0.x*w0 + b0.y*w1 + b1.x*w2 + b1.y*w3 + b2.x*w4 + b2.y*w5;

    float m = fmaxf(d0, d1);
#pragma unroll
    for (int off = 32; off >= 1; off >>= 1)
        m = fmaxf(m, __shfl_xor(m, off, 64));

    float e0 = __expf((d0 - m) * INV_T);
    float e1 = __expf((d1 - m) * INV_T);
    float num = e0 * d0 + e1 * d1;
    float den = e0 + e1;
#pragma unroll
    for (int off = 32; off >= 1; off >>= 1) {
        num += __shfl_xor(num, off, 64);
        den += __shfl_xor(den, off, 64);
    }

    if (lane == 0)
        V[cell] = num / den;   // plain store; dispatch boundary publishes it
}

// ---------------- Kernel 2: per-b epilogue ----------------
// 256 blocks x 128 threads; one thread per b computes BOTH sides (the two
// sides share the same 80B phi record -> halves phi fetch vs one-thread-per-
// output) and writes a coalesced float2.
__global__ __launch_bounds__(128) void out_kernel(
    const float* __restrict__ phi, const float* __restrict__ w,
    const float* __restrict__ V, float* __restrict__ out)
{
    const int tid = threadIdx.x;
    const int b = blockIdx.x * 128 + tid;   // 0..32767

    // phi layout: [B, 2, 10] -> 20 floats per b, 16B-aligned (80B stride).
    // 5 independent float4 loads; issue first to overlap with V staging.
    const float4* p4 = (const float4*)(phi + (size_t)b * 20);
    float4 c0 = p4[0];  // t0: f0 f1 f2 f3
    float4 c1 = p4[1];  // t0: f4 f5 x_ss y_ss
    float4 c2 = p4[2];  // t0: x_es y_es | t1: f0 f1
    float4 c3 = p4[3];  // t1: f2 f3 f4 f5
    float4 c4 = p4[4];  // t1: x_ss y_ss x_es y_es

    const float w0 = w[0], w1 = w[1], w2 = w[2],
                w3 = w[3], w4 = w[4], w5 = w[5];

    // Stage V into LDS with float4 loads: 225 transactions/block, 2
    // independent rounds (no serial chain). V is MALL-hot from kernel 1.
    __shared__ float Vs[CELLS];
    {
        float4* Vs4 = (float4*)Vs;
        const float4* V4 = (const float4*)V;
#pragma unroll
        for (int i = tid; i < CELLS / 4; i += 128)
            Vs4[i] = V4[i];
    }
    __syncthreads();

    float pr0 = c0.x*w0 + c0.y*w1 + c0.z*w2 + c0.w*w3 + c1.x*w4 + c1.y*w5;
    float pr1 = c2.z*w0 + c2.w*w1 + c3.x*w2 + c3.y*w3 + c3.z*w4 + c3.w*w5;

    int iss0 = (int)c1.z * Y_N + (int)c1.w;
    int ies0 = (int)c2.x * Y_N + (int)c2.y;
    int iss1 = (int)c4.x * Y_N + (int)c4.y;
    int ies1 = (int)c4.z * Y_N + (int)c4.w;

    float d0 = pr0 + Vs[ies0] - Vs[iss0];
    float d1 = pr1 + Vs[ies1] - Vs[iss1];

    // Same per-side formulas as the verified kernel (bitwise-identical):
    // side 0: x = d0 - d1; side 1: x = d1 - d0.
    float x0 = d0 - d1;
    float x1 = d1 - d0;
    float2 o;
    o.x = 1.0f / (1.0f + expf(-x0));
    o.y = 1.0f / (1.0f + expf(-x1));
    ((float2*)out)[b] = o;
}

// ---------------------------------------------------------------------------
extern "C" void kernel_launch(void* const* d_in, const int* in_sizes, int n_in,
                              void* d_out, int out_size, void* d_ws, size_t ws_size,
                              hipStream_t stream) {
    const float* phi = (const float*)d_in[0];   // (B, 2, 10)
    const float* sf  = (const float*)d_in[1];   // (P, X, Y, F)
    const float* w   = (const float*)d_in[2];   // (F,)
    float* out = (float*)d_out;                 // (B, 2, 1)
    float* V   = (float*)d_ws;                  // 900 floats scratch

    v_kernel<<<225, 256, 0, stream>>>(sf, w, V);
    out_kernel<<<256, 128, 0, stream>>>(phi, w, V, out);
}